// Round 5
// baseline (268.439 us; speedup 1.0000x reference)
//
#include <hip/hip_runtime.h>
#include <hip/hip_bf16.h>

#define BQ   32768
#define TT   25
#define DIN  4
#define HH   32
#define GG   128
#define NBR  5
#define HIDD 64
#define WPB  8      // waves per block, all same branch, sharing LDS weights
#define LOG2E    1.4426950408889634f
#define TWOLOG2E 2.8853900817779268f

using bfrag = __attribute__((ext_vector_type(8))) short;  // 8 bf16 (4 VGPRs)
using accf  = __attribute__((ext_vector_type(4))) float;  // 4 f32 acc
using f2    = __attribute__((ext_vector_type(2))) float;  // v_pk_* candidate

__device__ __forceinline__ float fexp2(float x){
#if __has_builtin(__builtin_amdgcn_exp2f)
  return __builtin_amdgcn_exp2f(x);
#else
  return exp2f(x);
#endif
}
__device__ __forceinline__ float frcpf(float x){
#if __has_builtin(__builtin_amdgcn_rcpf)
  return __builtin_amdgcn_rcpf(x);
#else
  return 1.0f / x;
#endif
}
__device__ __forceinline__ unsigned short fb(float f){  // f32 -> bf16 bits, RNE
  unsigned u = __builtin_bit_cast(unsigned, f);
  u += 0x7fffu + ((u >> 16) & 1u);
  return (unsigned short)(u >> 16);
}
__device__ __forceinline__ bfrag pack8s(const float* p, float s){
  bfrag w;
#pragma unroll
  for (int j = 0; j < 8; ++j) w[j] = (short)fb(p[j] * s);
  return w;
}
__device__ __forceinline__ accf mma(bfrag a, bfrag b, accf c){
  return __builtin_amdgcn_mfma_f32_16x16x32_bf16(a, b, c, 0, 0, 0);
}
// v_cvt_pk_bf16_f32: pack 2 f32 -> 2 bf16 in one dword (RNE). No builtin on
// gfx950 (guide T12/m240) -> inline asm (non-volatile: schedulable, DCE-able).
__device__ __forceinline__ unsigned cvtpk(f2 h){
  unsigned r;
  asm("v_cvt_pk_bf16_f32 %0, %1, %2" : "=v"(r) : "v"(h.x), "v"(h.y));
  return r;
}

// Paired LSTM cell (rows r,r+1 -> consecutive VGPRs -> v_pk_* math).
// Gates pre-scaled: i,f,o by log2e; g by 2log2e. cs in 2log2e units.
// Merged-rcp + rcp pair-merge (1/a,1/b = rcp(a*b)*{b,a}): 10 exp2 + 2 rcp
// per pair -- the exp count is the mathematical floor (5 nonlin/element).
// Site-2 protected by fmed3 clamp of cs to +-40 (semantics preserved).
__device__ __forceinline__ f2 cellh2(f2 iv, f2 fv, f2 gv, f2 ov, f2& cs){
  const f2 one = {1.0f, 1.0f};
  f2 ei = {fexp2(-iv.x), fexp2(-iv.y)};
  f2 ef = {fexp2(-fv.x), fexp2(-fv.y)};
  f2 t  = {fexp2(gv.x),  fexp2(gv.y)};
  f2 df = one + ef;                                  // 1/sig(f) denom
  f2 d1 = (one + ei) * (t + one);                    // sig(i)*tanh(g) denom
  f2 num = cs * d1 + (f2){TWOLOG2E, TWOLOG2E} * ((t - one) * df);
  f2 den = df * d1;
  float pr = frcpf(den.x * den.y);                   // paired rcp site 1
  f2 cp = num * (f2){den.y * pr, den.x * pr};
  cp.x = __builtin_amdgcn_fmed3f(cp.x, -40.f, 40.f);
  cp.y = __builtin_amdgcn_fmed3f(cp.y, -40.f, 40.f);
  cs = cp;
  f2 eo = {fexp2(-ov.x), fexp2(-ov.y)};
  f2 tc = {fexp2(cp.x), fexp2(cp.y)};
  f2 d3 = (one + eo) * (tc + one);
  float p3 = frcpf(d3.x * d3.y);                     // paired rcp site 2
  return (tc - one) * (f2){d3.y * p3, d3.x * p3};    // sig(o)*tanh(c)
}
template<int RP>
__device__ __forceinline__ f2 mkf2(accf a){ return (f2){a[RP*2], a[RP*2+1]}; }
__device__ __forceinline__ f2 addb(f2 a, float b){ return (f2){a.x + b, a.y + b}; }

// Compiler-visible b16 stores (lo + hi>>16 -> ds_write_b16/_d16_hi). Round-4:
// replacing volatile-asm stores with these de-fenced the step body (-3%).
#define CELLSTORE(PK, UT, RP) do {                                        \
    unsigned _pk = (PK);                                                  \
    int _b = (quad * 4 + (RP) * 2) * 40 + (UT) * 16 + col;                \
    hb[_b]      = (unsigned short)_pk;                                    \
    hb[_b + 40] = (unsigned short)(_pk >> 16);                            \
  } while (0)

// LDS layout (shorts):
//   wB[3][8][64][8] : Whh0/Wih1/Whh1 frag-arranged, scaled        = 12288
//   wX[8][16][8]    : layer-0 x-weight+bias frags                 =  1024
//   hb[WPB][640]    : per-wave h scratch [16][40] -- shared by layer 0/1
//                     and the MLP head (anti-dependencies keep it ordered).
// total 18432 shorts = 36864 B.
// HISTORY: R2/R3 proved occupancy is NOT the lever (3->4 blocks/CU legal,
// dur/occ unchanged): CU pipes saturated. R4 model: trans ops (~16cyc) are
// ~75% of VALU busy (irreducible); the lever left is taking MFMA execute
// OFF the critical path (VALU 73 + MFMA 19 ~ additive today).
#define SMEM_SH 18432

// ROUND-5: software-pipelined recurrence. Per iteration:
//   cell0(acc0) -> burst G1 (aH1@Whh1 first: covers h0 LDS-read latency;
//   then aH0@Wih1) -> burst G0(s+1) REUSING acc0's registers (dead after
//   cell0; no copy, no ping-pong) -> sched_barrier -> cell1(t1).
// All 32 MFMAs/step execute under cell1's ~470-cycle trans chain; next
// iteration's cell0 consumes MFMA results completed an entire cell1 ago.
// VGPR: acc0(32)+t1(32) live through cell1 => ~130 regs. launch_bounds
// (512,3) caps at 170 to avoid spills (spills >> lost occupancy here;
// effective occupancy is ~12 waves/CU regardless, see R2/R3).
__global__ __launch_bounds__(512, 3) void lstm_kernel(
    const float* __restrict__ x,    const float* __restrict__ mask,
    const float* __restrict__ Wih0, const float* __restrict__ Whh0,
    const float* __restrict__ bih0, const float* __restrict__ bhh0,
    const float* __restrict__ Wih1, const float* __restrict__ Whh1,
    const float* __restrict__ bih1, const float* __restrict__ bhh1,
    const float* __restrict__ W1,   const float* __restrict__ b1,
    const float* __restrict__ W2,   const float* __restrict__ b2,
    float* __restrict__ out)
{
  __shared__ __align__(16) unsigned short smem[SMEM_SH];
  unsigned short* wB = smem;
  unsigned short* wX = smem + 12288;
  const int tid  = threadIdx.x;
  const int wave = tid >> 6, lane = tid & 63;
  const int col  = lane & 15, quad = lane >> 4;
  // LPT: branch 4 (L=25) blocks dispatch first; short branches backfill tail.
  const int branch = 4 - (int)(blockIdx.x >> 8);
  const int tile   = (int)(blockIdx.x & 255) * WPB + wave;
  const int batch0 = tile * 16;
  const int L = (branch + 1) * 5, t0 = TT - L;
  unsigned short* hb = smem + 13312 + wave * 640;    // [16][40] shared scratch

  // ---- stage the three 128x32 matrices into LDS frags (coalesced reads) ----
  {
    const float* srcs[3] = { Whh0 + branch * GG * HH,
                             Wih1 + branch * GG * HH,
                             Whh1 + branch * GG * HH };
#pragma unroll
    for (int m = 0; m < 3; ++m) {
      const float* src = srcs[m];
#pragma unroll
      for (int i = 0; i < 8; ++i) {
        int v = tid + i * 512;                 // 0..4095
        float f = src[v];
        int g = v >> 5, k = v & 31;            // gate row, k index
        float sc = ((g >> 5) == 2) ? TWOLOG2E : LOG2E;   // 'g' gate rows 64..95
        int nt = g >> 4, cv = g & 15, q = k >> 3, j = k & 7;
        wB[((m * 8 + nt) * 64 + q * 16 + cv) * 8 + j] = fb(f * sc);
      }
    }
    if (tid < 128) {   // wX: x-weights (k<4) + fused layer-0 bias (k=4)
      int nt = tid >> 4, cv = tid & 15, g = nt * 16 + cv;
      float sc = ((g >> 5) == 2) ? TWOLOG2E : LOG2E;
      const float* q4 = Wih0 + branch * GG * DIN + g * DIN;
      unsigned short* d = wX + tid * 8;
      d[0] = fb(q4[0] * sc); d[1] = fb(q4[1] * sc);
      d[2] = fb(q4[2] * sc); d[3] = fb(q4[3] * sc);
      d[4] = fb((bih0[branch * GG + g] + bhh0[branch * GG + g]) * sc);
      d[5] = 0; d[6] = 0; d[7] = 0;
    }
  }
  float bias1[8];
#pragma unroll
  for (int nt = 0; nt < 8; ++nt) {
    int g = nt * 16 + col;
    float sc = ((g >> 5) == 2) ? TWOLOG2E : LOG2E;
    bias1[nt] = (bih1[branch * GG + g] + bhh1[branch * GG + g]) * sc;
  }
  __syncthreads();   // the ONLY block barrier: weights staged

  const accf zacc = {0.f, 0.f, 0.f, 0.f};
  const f2 zf2 = {0.f, 0.f};
  bfrag aH0 = {0,0,0,0,0,0,0,0}, aH1 = {0,0,0,0,0,0,0,0};
  f2 c0[2][2] = {{zf2, zf2}, {zf2, zf2}};   // [ut][rpair]
  f2 c1[2][2] = {{zf2, zf2}, {zf2, zf2}};

  const float* xrow = x    + (size_t)(batch0 + col) * (TT * DIN);
  const float* mrow = mask + (size_t)(batch0 + col) * (TT * DIN);
  float4 xv, mv;
  if (quad == 0) {   // step-0 x
    xv = *reinterpret_cast<const float4*>(xrow + t0 * 4);
    mv = *reinterpret_cast<const float4*>(mrow + t0 * 4);
  }

  // quads 1-3 keep ax = 0 (their A rows contribute nothing at k>=8, so wX
  // garbage at k>=8 is multiplied by zero -- unconditional bx loads OK).
  bfrag ax = {0,0,0,0,0,0,0,0};
  accf acc0[8];   // G0 gate accumulators; refilled in-place each iteration

  // ---- prologue: acc0 = G0(0) = xm(t0)@wX (+bias); h0(-1)=0 so no Whh0 ----
  if (quad == 0) {
    union { bfrag f; unsigned u[4]; } axu;
    axu.u[0] = cvtpk((f2){xv.x * mv.x, xv.y * mv.y});
    axu.u[1] = cvtpk((f2){xv.z * mv.z, xv.w * mv.w});
    axu.u[2] = 0x3F80u;   // elem4 = bf16 1.0 (bias lane)
    axu.u[3] = 0u;
    ax = axu.f;
    if (L > 1) {   // prefetch step-1 x
      xv = *reinterpret_cast<const float4*>(xrow + (t0 + 1) * 4);
      mv = *reinterpret_cast<const float4*>(mrow + (t0 + 1) * 4);
    }
  }
#pragma unroll
  for (int nt = 0; nt < 8; ++nt) {
    bfrag bx = *reinterpret_cast<const bfrag*>(wX + (nt * 16 + col) * 8);
    acc0[nt] = mma(ax, bx, zacc);
  }

  for (int s = 0; s < L; ++s) {
    // ---- cell0: acc0 -> h0(s) (acc0's MFMAs completed under prev cell1) ----
    {
      f2 h;
      h = cellh2(mkf2<0>(acc0[0]), mkf2<0>(acc0[2]), mkf2<0>(acc0[4]), mkf2<0>(acc0[6]), c0[0][0]);
      CELLSTORE(cvtpk(h), 0, 0);
      h = cellh2(mkf2<1>(acc0[0]), mkf2<1>(acc0[2]), mkf2<1>(acc0[4]), mkf2<1>(acc0[6]), c0[0][1]);
      CELLSTORE(cvtpk(h), 0, 1);
      h = cellh2(mkf2<0>(acc0[1]), mkf2<0>(acc0[3]), mkf2<0>(acc0[5]), mkf2<0>(acc0[7]), c0[1][0]);
      CELLSTORE(cvtpk(h), 1, 0);
      h = cellh2(mkf2<1>(acc0[1]), mkf2<1>(acc0[3]), mkf2<1>(acc0[5]), mkf2<1>(acc0[7]), c0[1][1]);
      CELLSTORE(cvtpk(h), 1, 1);
    }
    aH0 = *reinterpret_cast<const bfrag*>(hb + col * 40 + quad * 8);  // h0(s)

    // ---- burst G1(s): aH1 part FIRST (independent of the aH0 read above,
    //      fills its ~120-cycle latency window), then aH0 part ----
    accf t1[8];
#pragma unroll
    for (int nt = 0; nt < 8; ++nt) {
      bfrag bw = *reinterpret_cast<const bfrag*>(wB + ((2 * 8 + nt) * 64 + quad * 16 + col) * 8);
      t1[nt] = mma(aH1, bw, zacc);                   // h1(s-1) @ Whh1
    }
#pragma unroll
    for (int nt = 0; nt < 8; ++nt) {
      bfrag bw = *reinterpret_cast<const bfrag*>(wB + ((1 * 8 + nt) * 64 + quad * 16 + col) * 8);
      t1[nt] = mma(aH0, bw, t1[nt]);                 // h0(s) @ Wih1
    }

    // ---- burst G0(s+1) into acc0 (dead since cell0): executes under cell1 ----
    if (s + 1 < L) {
      if (quad == 0) {
        union { bfrag f; unsigned u[4]; } axu;
        axu.u[0] = cvtpk((f2){xv.x * mv.x, xv.y * mv.y});
        axu.u[1] = cvtpk((f2){xv.z * mv.z, xv.w * mv.w});
        axu.u[2] = 0x3F80u;
        axu.u[3] = 0u;
        ax = axu.f;
        if (s + 2 < L) {   // prefetch step s+2 x
          xv = *reinterpret_cast<const float4*>(xrow + (t0 + s + 2) * 4);
          mv = *reinterpret_cast<const float4*>(mrow + (t0 + s + 2) * 4);
        }
      }
#pragma unroll
      for (int nt = 0; nt < 8; ++nt) {
        bfrag bx = *reinterpret_cast<const bfrag*>(wX + (nt * 16 + col) * 8);
        acc0[nt] = mma(ax, bx, zacc);                // xm(s+1)@wX + bias
      }
#pragma unroll
      for (int nt = 0; nt < 8; ++nt) {
        bfrag bw = *reinterpret_cast<const bfrag*>(wB + ((0 * 8 + nt) * 64 + quad * 16 + col) * 8);
        acc0[nt] = mma(aH0, bw, acc0[nt]);           // h0(s) @ Whh0
      }
    }
    // keep the G0(s+1) burst ABOVE cell1 in the schedule (its results are
    // not needed until next iteration -- without this the scheduler may
    // sink it below cell1, re-exposing MFMA latency to cell0(s+1)):
    __builtin_amdgcn_sched_barrier(0);

    // ---- cell1: t1 (+bias1) -> h1(s); 24 MFMAs in flight under this ----
    {
      f2 h;
      h = cellh2(addb(mkf2<0>(t1[0]), bias1[0]), addb(mkf2<0>(t1[2]), bias1[2]),
                 addb(mkf2<0>(t1[4]), bias1[4]), addb(mkf2<0>(t1[6]), bias1[6]), c1[0][0]);
      CELLSTORE(cvtpk(h), 0, 0);
      h = cellh2(addb(mkf2<1>(t1[0]), bias1[0]), addb(mkf2<1>(t1[2]), bias1[2]),
                 addb(mkf2<1>(t1[4]), bias1[4]), addb(mkf2<1>(t1[6]), bias1[6]), c1[0][1]);
      CELLSTORE(cvtpk(h), 0, 1);
      h = cellh2(addb(mkf2<0>(t1[1]), bias1[1]), addb(mkf2<0>(t1[3]), bias1[3]),
                 addb(mkf2<0>(t1[5]), bias1[5]), addb(mkf2<0>(t1[7]), bias1[7]), c1[1][0]);
      CELLSTORE(cvtpk(h), 1, 0);
      h = cellh2(addb(mkf2<1>(t1[1]), bias1[1]), addb(mkf2<1>(t1[3]), bias1[3]),
                 addb(mkf2<1>(t1[5]), bias1[5]), addb(mkf2<1>(t1[7]), bias1[7]), c1[1][1]);
      CELLSTORE(cvtpk(h), 1, 1);
    }
    aH1 = *reinterpret_cast<const bfrag*>(hb + col * 40 + quad * 8);  // h1(s)
  }

  // ---- MLP head: tmp = gelu(h1@W1T + b1); out = tmp@W2T + b2 ----
  // fcb reuses hb ([16][40], 32 cols per phase): write cols 0-31, read af0,
  // then overwrite with cols 32-63, read af1 (anti-dependencies keep order).
  unsigned short* fcb = hb;
  accf t1h[4];
#pragma unroll
  for (int nt = 0; nt < 4; ++nt) {
    const int n = nt * 16 + col;
    bfrag bw1 = pack8s(W1 + n * HH + quad * 8, 1.0f);
    t1h[nt] = (accf){b1[n], b1[n], b1[n], b1[n]};
    t1h[nt] = mma(aH1, bw1, t1h[nt]);
  }
#pragma unroll
  for (int nt = 0; nt < 2; ++nt)
#pragma unroll
    for (int r = 0; r < 4; ++r) {
      float v = t1h[nt][r];
      v = 0.5f * v * (1.0f + erff(v * 0.70710678f));      // exact gelu
      fcb[(quad * 4 + r) * 40 + nt * 16 + col] = fb(v);
    }
  bfrag af0 = *reinterpret_cast<const bfrag*>(fcb + col * 40 + quad * 8);   // k 0..31
#pragma unroll
  for (int nt = 2; nt < 4; ++nt)
#pragma unroll
    for (int r = 0; r < 4; ++r) {
      float v = t1h[nt][r];
      v = 0.5f * v * (1.0f + erff(v * 0.70710678f));      // exact gelu
      fcb[(quad * 4 + r) * 40 + (nt - 2) * 16 + col] = fb(v);
    }
  bfrag af1 = *reinterpret_cast<const bfrag*>(fcb + col * 40 + quad * 8);   // k 32..63
  accf o[4];
#pragma unroll
  for (int nt = 0; nt < 4; ++nt) {
    const int n = nt * 16 + col;
    bfrag bw2a = pack8s(W2 + n * HIDD + quad * 8, 1.0f);
    bfrag bw2b = pack8s(W2 + n * HIDD + 32 + quad * 8, 1.0f);
    o[nt] = (accf){b2[n], b2[n], b2[n], b2[n]};
    o[nt] = mma(af0, bw2a, o[nt]);
    o[nt] = mma(af1, bw2b, o[nt]);
  }
#pragma unroll
  for (int nt = 0; nt < 4; ++nt)
#pragma unroll
    for (int r = 0; r < 4; ++r) {
      const int row = quad * 4 + r;
      out[(size_t)((batch0 + row) * NBR + branch) * HIDD + nt * 16 + col] = o[nt][r];
    }
}

extern "C" void kernel_launch(void* const* d_in, const int* in_sizes, int n_in,
                              void* d_out, int out_size, void* d_ws, size_t ws_size,
                              hipStream_t stream) {
  const float* x    = (const float*)d_in[0];
  const float* mask = (const float*)d_in[1];
  const float* Wih0 = (const float*)d_in[2];
  const float* Whh0 = (const float*)d_in[3];
  const float* bih0 = (const float*)d_in[4];
  const float* bhh0 = (const float*)d_in[5];
  const float* Wih1 = (const float*)d_in[6];
  const float* Whh1 = (const float*)d_in[7];
  const float* bih1 = (const float*)d_in[8];
  const float* bhh1 = (const float*)d_in[9];
  const float* W1   = (const float*)d_in[10];
  const float* b1   = (const float*)d_in[11];
  const float* W2   = (const float*)d_in[12];
  const float* b2   = (const float*)d_in[13];
  float* out = (float*)d_out;

  const int nblocks = (BQ / (16 * WPB)) * NBR;   // 256 * 5 = 1280 blocks x 512 thr
  lstm_kernel<<<nblocks, 512, 0, stream>>>(x, mask, Wih0, Whh0, bih0, bhh0,
                                           Wih1, Whh1, bih1, bhh1, W1, b1, W2, b2, out);
}

// Round 6
// 249.155 us; speedup vs baseline: 1.0774x; 1.0774x over previous
//
#include <hip/hip_runtime.h>
#include <hip/hip_bf16.h>

#define BQ   32768
#define TT   25
#define DIN  4
#define HH   32
#define GG   128
#define NBR  5
#define HIDD 64
#define WPB  8      // waves per block, all same branch, sharing LDS weights
#define LOG2E    1.4426950408889634f
#define TWOLOG2E 2.8853900817779268f

using bfrag = __attribute__((ext_vector_type(8))) short;  // 8 bf16 (4 VGPRs)
using accf  = __attribute__((ext_vector_type(4))) float;  // 4 f32 acc
using f2    = __attribute__((ext_vector_type(2))) float;  // v_pk_* candidate

__device__ __forceinline__ float fexp2(float x){
#if __has_builtin(__builtin_amdgcn_exp2f)
  return __builtin_amdgcn_exp2f(x);
#else
  return exp2f(x);
#endif
}
__device__ __forceinline__ float frcpf(float x){
#if __has_builtin(__builtin_amdgcn_rcpf)
  return __builtin_amdgcn_rcpf(x);
#else
  return 1.0f / x;
#endif
}
__device__ __forceinline__ unsigned short fb(float f){  // f32 -> bf16 bits, RNE
  unsigned u = __builtin_bit_cast(unsigned, f);
  u += 0x7fffu + ((u >> 16) & 1u);
  return (unsigned short)(u >> 16);
}
__device__ __forceinline__ bfrag pack8s(const float* p, float s){
  bfrag w;
#pragma unroll
  for (int j = 0; j < 8; ++j) w[j] = (short)fb(p[j] * s);
  return w;
}
__device__ __forceinline__ accf mma(bfrag a, bfrag b, accf c){
  return __builtin_amdgcn_mfma_f32_16x16x32_bf16(a, b, c, 0, 0, 0);
}
// v_cvt_pk_bf16_f32: pack 2 f32 -> 2 bf16 in one dword (RNE). No builtin on
// gfx950 (guide T12/m240) -> inline asm (non-volatile: schedulable, DCE-able).
__device__ __forceinline__ unsigned cvtpk(f2 h){
  unsigned r;
  asm("v_cvt_pk_bf16_f32 %0, %1, %2" : "=v"(r) : "v"(h.x), "v"(h.y));
  return r;
}

// Paired LSTM cell (rows r,r+1 -> consecutive VGPRs -> v_pk_* math).
// Gates pre-scaled: i,f,o by log2e; g by 2log2e. cs in 2log2e units.
// Merged-rcp + rcp pair-merge (1/a,1/b = rcp(a*b)*{b,a}): 10 exp2 + 2 rcp
// per pair -- the exp count is the mathematical floor (5 nonlin/element).
// Site-2 protected by fmed3 clamp of cs to +-40 (semantics preserved).
__device__ __forceinline__ f2 cellh2(f2 iv, f2 fv, f2 gv, f2 ov, f2& cs){
  const f2 one = {1.0f, 1.0f};
  f2 ei = {fexp2(-iv.x), fexp2(-iv.y)};
  f2 ef = {fexp2(-fv.x), fexp2(-fv.y)};
  f2 t  = {fexp2(gv.x),  fexp2(gv.y)};
  f2 df = one + ef;                                  // 1/sig(f) denom
  f2 d1 = (one + ei) * (t + one);                    // sig(i)*tanh(g) denom
  f2 num = cs * d1 + (f2){TWOLOG2E, TWOLOG2E} * ((t - one) * df);
  f2 den = df * d1;
  float pr = frcpf(den.x * den.y);                   // paired rcp site 1
  f2 cp = num * (f2){den.y * pr, den.x * pr};
  cp.x = __builtin_amdgcn_fmed3f(cp.x, -40.f, 40.f);
  cp.y = __builtin_amdgcn_fmed3f(cp.y, -40.f, 40.f);
  cs = cp;
  f2 eo = {fexp2(-ov.x), fexp2(-ov.y)};
  f2 tc = {fexp2(cp.x), fexp2(cp.y)};
  f2 d3 = (one + eo) * (tc + one);
  float p3 = frcpf(d3.x * d3.y);                     // paired rcp site 2
  return (tc - one) * (f2){d3.y * p3, d3.x * p3};    // sig(o)*tanh(c)
}
template<int RP>
__device__ __forceinline__ f2 mkf2(accf a){ return (f2){a[RP*2], a[RP*2+1]}; }
__device__ __forceinline__ f2 addb(f2 a, float b){ return (f2){a.x + b, a.y + b}; }

// Compiler-visible b16 stores (lo + hi>>16 -> ds_write_b16/_d16_hi). Round-4:
// replacing volatile-asm stores with these de-fenced the step body (-3%).
#define CELLSTORE(PK, UT, RP) do {                                        \
    unsigned _pk = (PK);                                                  \
    int _b = (quad * 4 + (RP) * 2) * 40 + (UT) * 16 + col;                \
    hb[_b]      = (unsigned short)_pk;                                    \
    hb[_b + 40] = (unsigned short)(_pk >> 16);                            \
  } while (0)

// LDS layout (shorts):
//   wB[3][8][64][8] : Whh0/Wih1/Whh1 frag-arranged, scaled        = 12288
//   wX[8][16][8]    : layer-0 x-weight+bias frags                 =  1024
//   hb[WPB][640]    : per-wave h scratch [16][40] -- shared by layer 0/1
//                     and the MLP head (anti-dependencies keep it ordered).
// total 18432 shorts = 36864 B.
// HISTORY (measured):
//  R2/R3: 3->4 blocks/CU legal -- dur/occ UNCHANGED (not LDS-limited).
//  R5: software-pipelining at (512,3) REGRESSED 189->205: reg growth cut
//      occupancy 38->26, VALUBusy 73.7->66.7. Absolute VALU-busy time is
//      invariant 137-148us across R2-R5 => wall = VALU-busy / VALUBusy%.
//  Levers: (a) cut VALU instr (esp. 96 quarter-rate trans/step), (b) raise
//  VALUBusy% by DE-PHASING waves (the ~27% slack = lockstep phase pattern:
//  all waves burst MFMA together, then all hammer the trans pipe together).
#define SMEM_SH 18432

// launch_bounds (512,4): proven config (R4=189us, VGPR 60). R5 proved going
// below 4 waves/SIMD costs more than any scheduling win. Keep VGPR <= 64.
__global__ __launch_bounds__(512, 4) void lstm_kernel(
    const float* __restrict__ x,    const float* __restrict__ mask,
    const float* __restrict__ Wih0, const float* __restrict__ Whh0,
    const float* __restrict__ bih0, const float* __restrict__ bhh0,
    const float* __restrict__ Wih1, const float* __restrict__ Whh1,
    const float* __restrict__ bih1, const float* __restrict__ bhh1,
    const float* __restrict__ W1,   const float* __restrict__ b1,
    const float* __restrict__ W2,   const float* __restrict__ b2,
    float* __restrict__ out)
{
  __shared__ __align__(16) unsigned short smem[SMEM_SH];
  unsigned short* wB = smem;
  unsigned short* wX = smem + 12288;
  const int tid  = threadIdx.x;
  const int wave = tid >> 6, lane = tid & 63;
  const int col  = lane & 15, quad = lane >> 4;
  // LPT: branch 4 (L=25) blocks dispatch first; short branches backfill tail.
  const int branch = 4 - (int)(blockIdx.x >> 8);
  const int tile   = (int)(blockIdx.x & 255) * WPB + wave;
  const int batch0 = tile * 16;
  const int L = (branch + 1) * 5, t0 = TT - L;
  unsigned short* hb = smem + 13312 + wave * 640;    // [16][40] shared scratch

  // ---- stage the three 128x32 matrices into LDS frags (coalesced reads) ----
  {
    const float* srcs[3] = { Whh0 + branch * GG * HH,
                             Wih1 + branch * GG * HH,
                             Whh1 + branch * GG * HH };
#pragma unroll
    for (int m = 0; m < 3; ++m) {
      const float* src = srcs[m];
#pragma unroll
      for (int i = 0; i < 8; ++i) {
        int v = tid + i * 512;                 // 0..4095
        float f = src[v];
        int g = v >> 5, k = v & 31;            // gate row, k index
        float sc = ((g >> 5) == 2) ? TWOLOG2E : LOG2E;   // 'g' gate rows 64..95
        int nt = g >> 4, cv = g & 15, q = k >> 3, j = k & 7;
        wB[((m * 8 + nt) * 64 + q * 16 + cv) * 8 + j] = fb(f * sc);
      }
    }
    if (tid < 128) {   // wX: x-weights (k<4) + fused layer-0 bias (k=4)
      int nt = tid >> 4, cv = tid & 15, g = nt * 16 + cv;
      float sc = ((g >> 5) == 2) ? TWOLOG2E : LOG2E;
      const float* q4 = Wih0 + branch * GG * DIN + g * DIN;
      unsigned short* d = wX + tid * 8;
      d[0] = fb(q4[0] * sc); d[1] = fb(q4[1] * sc);
      d[2] = fb(q4[2] * sc); d[3] = fb(q4[3] * sc);
      d[4] = fb((bih0[branch * GG + g] + bhh0[branch * GG + g]) * sc);
      d[5] = 0; d[6] = 0; d[7] = 0;
    }
  }
  float bias1[8];
#pragma unroll
  for (int nt = 0; nt < 8; ++nt) {
    int g = nt * 16 + col;
    float sc = ((g >> 5) == 2) ? TWOLOG2E : LOG2E;
    bias1[nt] = (bih1[branch * GG + g] + bhh1[branch * GG + g]) * sc;
  }
  __syncthreads();   // the ONLY block barrier: weights staged

  // ROUND-6: DE-PHASE the waves. All waves run an identical-duration step
  // (~2200 cyc: MFMA burst ~600 + two trans-heavy cell phases ~1600), and
  // they enter the loop together => lockstep phases: VALU idles during the
  // common MFMA bursts (the ~27% non-busy slack), trans pipe oversubscribed
  // during the common cell phases. A one-time per-wave offset (persists,
  // since per-step duration is wave-invariant) anti-aligns the phases so
  // one wave's cell math fills the VALU while another is in its burst.
  // s_sleep is off-pipe; one-time cost <= 0.72us for 3/4 of the waves.
  {
    const int ph = wave & 3;
    if (ph == 1)      __builtin_amdgcn_s_sleep(9);    //  576 cyc
    else if (ph == 2) __builtin_amdgcn_s_sleep(18);   // 1152 cyc
    else if (ph == 3) __builtin_amdgcn_s_sleep(27);   // 1728 cyc
  }

  const accf zacc = {0.f, 0.f, 0.f, 0.f};
  const f2 zf2 = {0.f, 0.f};
  bfrag aH0 = {0,0,0,0,0,0,0,0}, aH1 = {0,0,0,0,0,0,0,0};
  f2 c0[2][2] = {{zf2, zf2}, {zf2, zf2}};   // [ut][rpair]
  f2 c1[2][2] = {{zf2, zf2}, {zf2, zf2}};

  const float* xrow = x    + (size_t)(batch0 + col) * (TT * DIN);
  const float* mrow = mask + (size_t)(batch0 + col) * (TT * DIN);
  float4 xv, mv;
  if (quad == 0) {   // prefetch step t0's x
    xv = *reinterpret_cast<const float4*>(xrow + t0 * 4);
    mv = *reinterpret_cast<const float4*>(mrow + t0 * 4);
  }

  // ax hoisted (zeros persist for quads 1-3; quad0 rewrites all 16B each
  // step). bx loaded UNCONDITIONALLY by all quads: quads 1-3 supply garbage
  // B rows at k>=8, but A is zero at k>=8 for every row, so garbage*0 = 0.
  bfrag ax = {0,0,0,0,0,0,0,0};

  for (int s = 0; s < L; ++s) {
    // ---------- layer 0 ----------
    if (quad == 0) {   // A[m=col][k]: k<4 = xm_t, k=4 = 1.0 (bias lane)
      union { bfrag f; unsigned u[4]; } axu;
      axu.u[0] = cvtpk((f2){xv.x * mv.x, xv.y * mv.y});
      axu.u[1] = cvtpk((f2){xv.z * mv.z, xv.w * mv.w});
      axu.u[2] = 0x3F80u;   // elem4 = bf16 1.0 (bias lane), elem5 = 0
      axu.u[3] = 0u;
      ax = axu.f;
      if (s + 1 < L) {   // prefetch next step
        xv = *reinterpret_cast<const float4*>(xrow + (t0 + s + 1) * 4);
        mv = *reinterpret_cast<const float4*>(mrow + (t0 + s + 1) * 4);
      }
    }
    accf acc[8];
#pragma unroll
    for (int nt = 0; nt < 8; ++nt) {         // x + bias via MFMA
      bfrag bx = *reinterpret_cast<const bfrag*>(wX + (nt * 16 + col) * 8);
      acc[nt] = mma(ax, bx, zacc);
    }
#pragma unroll
    for (int nt = 0; nt < 8; ++nt) {
      bfrag bw = *reinterpret_cast<const bfrag*>(wB + ((0 * 8 + nt) * 64 + quad * 16 + col) * 8);
      acc[nt] = mma(aH0, bw, acc[nt]);
    }
    // cell math + h0 store (rows quad*4+rp*2+{0,1}, col ut*16+col)
    {
      f2 h;
      h = cellh2(mkf2<0>(acc[0]), mkf2<0>(acc[2]), mkf2<0>(acc[4]), mkf2<0>(acc[6]), c0[0][0]);
      CELLSTORE(cvtpk(h), 0, 0);
      h = cellh2(mkf2<1>(acc[0]), mkf2<1>(acc[2]), mkf2<1>(acc[4]), mkf2<1>(acc[6]), c0[0][1]);
      CELLSTORE(cvtpk(h), 0, 1);
      h = cellh2(mkf2<0>(acc[1]), mkf2<0>(acc[3]), mkf2<0>(acc[5]), mkf2<0>(acc[7]), c0[1][0]);
      CELLSTORE(cvtpk(h), 1, 0);
      h = cellh2(mkf2<1>(acc[1]), mkf2<1>(acc[3]), mkf2<1>(acc[5]), mkf2<1>(acc[7]), c0[1][1]);
      CELLSTORE(cvtpk(h), 1, 1);
    }
    aH0 = *reinterpret_cast<const bfrag*>(hb + col * 40 + quad * 8);  // A-layout (in-wave DS order)
    // ---------- layer 1 ---------- (bias folded in at extraction; h1 reuses
    // the SAME hb buffer: the aH0 load above is an anti-dependency the
    // compiler must respect before these stores)
#pragma unroll
    for (int nt = 0; nt < 8; ++nt) {
      bfrag bw = *reinterpret_cast<const bfrag*>(wB + ((1 * 8 + nt) * 64 + quad * 16 + col) * 8);
      acc[nt] = mma(aH0, bw, zacc);
    }
#pragma unroll
    for (int nt = 0; nt < 8; ++nt) {
      bfrag bw = *reinterpret_cast<const bfrag*>(wB + ((2 * 8 + nt) * 64 + quad * 16 + col) * 8);
      acc[nt] = mma(aH1, bw, acc[nt]);
    }
    {
      f2 h;
      h = cellh2(addb(mkf2<0>(acc[0]), bias1[0]), addb(mkf2<0>(acc[2]), bias1[2]),
                 addb(mkf2<0>(acc[4]), bias1[4]), addb(mkf2<0>(acc[6]), bias1[6]), c1[0][0]);
      CELLSTORE(cvtpk(h), 0, 0);
      h = cellh2(addb(mkf2<1>(acc[0]), bias1[0]), addb(mkf2<1>(acc[2]), bias1[2]),
                 addb(mkf2<1>(acc[4]), bias1[4]), addb(mkf2<1>(acc[6]), bias1[6]), c1[0][1]);
      CELLSTORE(cvtpk(h), 0, 1);
      h = cellh2(addb(mkf2<0>(acc[1]), bias1[1]), addb(mkf2<0>(acc[3]), bias1[3]),
                 addb(mkf2<0>(acc[5]), bias1[5]), addb(mkf2<0>(acc[7]), bias1[7]), c1[1][0]);
      CELLSTORE(cvtpk(h), 1, 0);
      h = cellh2(addb(mkf2<1>(acc[1]), bias1[1]), addb(mkf2<1>(acc[3]), bias1[3]),
                 addb(mkf2<1>(acc[5]), bias1[5]), addb(mkf2<1>(acc[7]), bias1[7]), c1[1][1]);
      CELLSTORE(cvtpk(h), 1, 1);
    }
    aH1 = *reinterpret_cast<const bfrag*>(hb + col * 40 + quad * 8);
  }

  // ---- MLP head: tmp = gelu(h1@W1T + b1); out = tmp@W2T + b2 ----
  // fcb reuses hb ([16][40], 32 cols per phase): write cols 0-31, read af0,
  // then overwrite with cols 32-63, read af1 (anti-dependencies keep order).
  unsigned short* fcb = hb;
  accf t1[4];
#pragma unroll
  for (int nt = 0; nt < 4; ++nt) {
    const int n = nt * 16 + col;
    bfrag bw1 = pack8s(W1 + n * HH + quad * 8, 1.0f);
    t1[nt] = (accf){b1[n], b1[n], b1[n], b1[n]};
    t1[nt] = mma(aH1, bw1, t1[nt]);
  }
#pragma unroll
  for (int nt = 0; nt < 2; ++nt)
#pragma unroll
    for (int r = 0; r < 4; ++r) {
      float v = t1[nt][r];
      v = 0.5f * v * (1.0f + erff(v * 0.70710678f));      // exact gelu
      fcb[(quad * 4 + r) * 40 + nt * 16 + col] = fb(v);
    }
  bfrag af0 = *reinterpret_cast<const bfrag*>(fcb + col * 40 + quad * 8);   // k 0..31
#pragma unroll
  for (int nt = 2; nt < 4; ++nt)
#pragma unroll
    for (int r = 0; r < 4; ++r) {
      float v = t1[nt][r];
      v = 0.5f * v * (1.0f + erff(v * 0.70710678f));      // exact gelu
      fcb[(quad * 4 + r) * 40 + (nt - 2) * 16 + col] = fb(v);
    }
  bfrag af1 = *reinterpret_cast<const bfrag*>(fcb + col * 40 + quad * 8);   // k 32..63
  accf o[4];
#pragma unroll
  for (int nt = 0; nt < 4; ++nt) {
    const int n = nt * 16 + col;
    bfrag bw2a = pack8s(W2 + n * HIDD + quad * 8, 1.0f);
    bfrag bw2b = pack8s(W2 + n * HIDD + 32 + quad * 8, 1.0f);
    o[nt] = (accf){b2[n], b2[n], b2[n], b2[n]};
    o[nt] = mma(af0, bw2a, o[nt]);
    o[nt] = mma(af1, bw2b, o[nt]);
  }
#pragma unroll
  for (int nt = 0; nt < 4; ++nt)
#pragma unroll
    for (int r = 0; r < 4; ++r) {
      const int row = quad * 4 + r;
      out[(size_t)((batch0 + row) * NBR + branch) * HIDD + nt * 16 + col] = o[nt][r];
    }
}

extern "C" void kernel_launch(void* const* d_in, const int* in_sizes, int n_in,
                              void* d_out, int out_size, void* d_ws, size_t ws_size,
                              hipStream_t stream) {
  const float* x    = (const float*)d_in[0];
  const float* mask = (const float*)d_in[1];
  const float* Wih0 = (const float*)d_in[2];
  const float* Whh0 = (const float*)d_in[3];
  const float* bih0 = (const float*)d_in[4];
  const float* bhh0 = (const float*)d_in[5];
  const float* Wih1 = (const float*)d_in[6];
  const float* Whh1 = (const float*)d_in[7];
  const float* bih1 = (const float*)d_in[8];
  const float* bhh1 = (const float*)d_in[9];
  const float* W1   = (const float*)d_in[10];
  const float* b1   = (const float*)d_in[11];
  const float* W2   = (const float*)d_in[12];
  const float* b2   = (const float*)d_in[13];
  float* out = (float*)d_out;

  const int nblocks = (BQ / (16 * WPB)) * NBR;   // 256 * 5 = 1280 blocks x 512 thr
  lstm_kernel<<<nblocks, 512, 0, stream>>>(x, mask, Wih0, Whh0, bih0, bhh0,
                                           Wih1, Whh1, bih1, bhh1, W1, b1, W2, b2, out);
}